// Round 14
// baseline (254.589 us; speedup 1.0000x reference)
//
#include <hip/hip_runtime.h>
#include <hip/hip_bf16.h>
#include <math.h>

#define BATCH 512
#define FEAT  256
#define NCLS  100000
#define SCALE_ 32.0f
#define M0_    0.5f
#define MMIN_  0.25f

#define BN 32                        // classes per tile (100000 = 3125*32, no edge)
#define NT32 3125                    // exact tile count
#define NSLOTS 512                   // class-tile slots (stride)
#define NPART 512                    // partial slots per sample
#define K4CHUNK 16
#define NK4 (NPART / K4CHUNK)        // 32

#define LOG2E_ 1.44269504088896f
#define K2C_   (SCALE_ * LOG2E_)     // 46.166...; fixed softmax max (log2 domain)

typedef unsigned short u16;
typedef short s16x8 __attribute__((ext_vector_type(8)));
typedef float f32x4 __attribute__((ext_vector_type(4)));

// ---- static device scratch ----
__device__ u16   g_fbf16[BATCH * FEAT];    // normalized features, bf16
__device__ float g_norms[BATCH];
__device__ float g_dot[BATCH];             // raw f32 feat . W[label]
__device__ float g_wn2[BATCH];             // ||W[label]||^2 (f32)
__device__ float g_psum[NPART * BATCH];    // fixed-max partial sums
__device__ float g_qs[NK4 * BATCH];

__device__ __forceinline__ u16 f2b(float x) {
  union { float f; unsigned u; } v; v.f = x;
  unsigned r = v.u + 0x7FFFu + ((v.u >> 16) & 1u);   // RNE
  return (u16)(r >> 16);
}

// packed f32x2 -> bf16x2 (lo = a, hi = b)
__device__ __forceinline__ unsigned pkbf16(float a, float b) {
  unsigned r;
  asm("v_cvt_pk_bf16_f32 %0, %1, %2" : "=v"(r) : "v"(a), "v"(b));
  return r;
}

__device__ __forceinline__ float ex2(float x) {
  return __builtin_amdgcn_exp2f(x);
}

// K12 (merged k1a + k2c, data-independent halves):
// blocks 0..127: per-row feature norm -> NORMALIZED bf16 row + g_norms.
// blocks 128..255: raw f32 dot(feat_i, W[label_i]) and ||W[label_i]||^2;
//   label width (int32 vs int64) detected locally per wave.
__global__ void k12(const float* __restrict__ feat, const float* __restrict__ wmat,
                    const void* __restrict__ labels) {
  int b = blockIdx.x;
  int wid = threadIdx.x >> 6, lane = threadIdx.x & 63;
  if (b < 128) {
    int row = b * 4 + wid;
    float4 f = ((const float4*)(feat + row * FEAT))[lane];
    float ss = f.x * f.x + f.y * f.y + f.z * f.z + f.w * f.w;
    #pragma unroll
    for (int d = 1; d < 64; d <<= 1) ss += __shfl_xor(ss, d, 64);
    float nrm = sqrtf(ss);
    float inv = 1.0f / fmaxf(nrm, 1e-12f);
    ushort4 h;
    h.x = f2b(f.x * inv); h.y = f2b(f.y * inv);
    h.z = f2b(f.z * inv); h.w = f2b(f.w * inv);
    ((ushort4*)(g_fbf16 + row * FEAT))[lane] = h;
    if (lane == 0) g_norms[row] = nrm;
  } else {
    int i = (b - 128) * 4 + wid;
    // label width detect (per-wave, no cross-kernel dep): odd 32-bit words of
    // the first 256 labels-as-int64 are all 0 iff labels are int64.
    const int* labw = (const int*)labels;
    int odd = 0;
    #pragma unroll
    for (int k = 0; k < 4; ++k) odd |= labw[2 * (k * 64 + lane) + 1];
    unsigned long long bl = __ballot(odd != 0);
    long long lab;
    if (bl != 0ULL) lab = (long long)((const int*)labels)[i];
    else            lab = ((const long long*)labels)[i];
    float4 a = ((const float4*)(feat + i * FEAT))[lane];
    float4 w = ((const float4*)(wmat + (size_t)lab * FEAT))[lane];
    float d  = a.x * w.x + a.y * w.y + a.z * w.z + a.w * w.w;
    float bb = w.x * w.x + w.y * w.y + w.z * w.z + w.w * w.w;
    #pragma unroll
    for (int t = 1; t < 64; t <<= 1) {
      d  += __shfl_xor(d, t, 64);
      bb += __shfl_xor(bb, t, 64);
    }
    if (lane == 0) { g_dot[i] = d; g_wn2[i] = bb; }
  }
}

// K3 (fused): 1024 blocks x 256 threads (4 waves). DECONFOUNDED residency
// test: bid -> (sh, nslot) mapped so same-nslot sh-pairs are exactly 256
// blocks apart (grp=bid>>8; sh=grp&1; nslot=(bid&255)+(grp>>1)*256). With
// round-robin block->CU assignment, CU c hosts {(sh0,c),(sh1,c), ...}:
// the same W tile stream -> cache dedupe (FETCH ~51 MB) at EITHER 2- or
// 4-block residency, so the time delta purely measures residency.
// Each wave owns 64 samples (fr[4][8] = 128 VGPR, m=4): each ds_read_b128
// of W feeds 4 MFMA. W read RAW f32, normalized in-flight, bf16 ->
// swizzled LDS (2x16 KB dbuf). LOAD(t+1) at iter start, FINISH between
// phases (T14). FIXED-MAX softmax in exp2 domain: plain sums; q-group sum
// once at end.

#define LOADC(TILE) do {                                                    \
    rowL_ = tid >> 4;                                                       \
    const float4* s0_ = (const float4*)(wmat + (size_t)((TILE) * BN + rowL_) * FEAT + (tid & 15) * 16);      \
    const float4* s1_ = (const float4*)(wmat + (size_t)((TILE) * BN + 16 + rowL_) * FEAT + (tid & 15) * 16); \
    v_[0] = s0_[0]; v_[1] = s0_[1]; v_[2] = s0_[2]; v_[3] = s0_[3];         \
    v_[4] = s1_[0]; v_[5] = s1_[1]; v_[6] = s1_[2]; v_[7] = s1_[3];         \
  } while (0)

#define FINHALF(NB, G, ROW) do {                                            \
    float ss_ = 0.0f;                                                       \
    _Pragma("unroll")                                                       \
    for (int k_ = 0; k_ < 4; ++k_) {                                        \
      float4 vv_ = v_[(G) * 4 + k_];                                        \
      ss_ += vv_.x * vv_.x + vv_.y * vv_.y + vv_.z * vv_.z + vv_.w * vv_.w; \
    }                                                                       \
    ss_ += __shfl_xor(ss_, 1, 64);                                          \
    ss_ += __shfl_xor(ss_, 2, 64);                                          \
    ss_ += __shfl_xor(ss_, 4, 64);                                          \
    ss_ += __shfl_xor(ss_, 8, 64);                                          \
    float inv_ = 1.0f / fmaxf(sqrtf(ss_), 1e-12f);                          \
    u16* dst_ = &Ws[NB][0] + (ROW) * FEAT;                                  \
    _Pragma("unroll")                                                       \
    for (int k_ = 0; k_ < 2; ++k_) {                                        \
      int jj_ = (tid & 15) * 2 + k_;                                        \
      float4 va_ = v_[(G) * 4 + 2 * k_], vb_ = v_[(G) * 4 + 2 * k_ + 1];    \
      int4 w4_;                                                             \
      w4_.x = (int)pkbf16(va_.x * inv_, va_.y * inv_);                      \
      w4_.y = (int)pkbf16(va_.z * inv_, va_.w * inv_);                      \
      w4_.z = (int)pkbf16(vb_.x * inv_, vb_.y * inv_);                      \
      w4_.w = (int)pkbf16(vb_.z * inv_, vb_.w * inv_);                      \
      *(int4*)(dst_ + ((jj_ ^ ((ROW) & 7)) * 8)) = w4_;                     \
    }                                                                       \
  } while (0)

#define FINISHC(NB) do {                                                    \
    FINHALF(NB, 0, rowL_);                                                  \
    FINHALF(NB, 1, 16 + rowL_);                                             \
  } while (0)

#define PHASE(p8) do {                                                      \
    f32x4 acc[4];                                                           \
    _Pragma("unroll")                                                       \
    for (int m = 0; m < 4; ++m) acc[m] = f32x4{0.0f, 0.0f, 0.0f, 0.0f};     \
    const u16* wb = &Ws[buf][0];                                            \
    const int row_ = (p8) * 16 + s;                                         \
    _Pragma("unroll")                                                       \
    for (int c = 0; c < 8; ++c) {                                           \
      int cc = c * 4 + q;                                                   \
      s16x8 wf = *(const s16x8*)(wb + row_ * FEAT + (cc ^ (row_ & 7)) * 8); \
      _Pragma("unroll")                                                     \
      for (int m = 0; m < 4; ++m)                                           \
        acc[m] = __builtin_amdgcn_mfma_f32_16x16x32_bf16(wf, fr[m][c], acc[m], 0, 0, 0); \
    }                                                                       \
    _Pragma("unroll")                                                       \
    for (int m = 0; m < 4; ++m) {                                           \
      float sl = ex2(fmaf(acc[m][0], K2C_, -K2C_))                          \
               + ex2(fmaf(acc[m][1], K2C_, -K2C_))                          \
               + ex2(fmaf(acc[m][2], K2C_, -K2C_))                          \
               + ex2(fmaf(acc[m][3], K2C_, -K2C_));                         \
      S[m] += sl;                                                           \
    }                                                                       \
  } while (0)

__global__ __launch_bounds__(256, 4) void k3(const float* __restrict__ wmat) {
  __shared__ __align__(16) u16 Ws[2][BN * FEAT];   // 2 x 16 KB

  const int tid  = threadIdx.x;
  const int lane = tid & 63, wid = tid >> 6;       // 4 waves
  const int s = lane & 15, q = lane >> 4;
  const int bid = blockIdx.x;
  const int grp = bid >> 8;                        // 0..3
  const int sh  = grp & 1;                         // sample half
  const int nslot = (bid & 255) + ((grp >> 1) << 8);   // 0..511
  const int niter = ((NT32 - 1 - nslot) >> 9) + 1; // 7 (nslot<53) or 6

  int rowL_;
  float4 v_[8];

  // prologue: stage tile `nslot` into buf 0
  LOADC(nslot); FINISHC(0);

  // feature fragments (B-operand): 64 samples per wave, register-resident.
  s16x8 fr[4][8];
  {
    const int srow = sh * 256 + wid * 64;
    #pragma unroll
    for (int m = 0; m < 4; ++m)
      #pragma unroll
      for (int c = 0; c < 8; ++c)
        fr[m][c] = *(const s16x8*)(g_fbf16 + (srow + m * 16 + s) * FEAT + c * 32 + q * 8);
  }

  float S[4] = {0.0f, 0.0f, 0.0f, 0.0f};

  __syncthreads();

  int buf = 0;
  for (int t = 0; t < niter; ++t) {
    const bool last = (t + 1 == niter);

    if (!last) LOADC(nslot + (t + 1) * NSLOTS);
    PHASE(0);
    if (!last) FINISHC(buf ^ 1);
    PHASE(1);
    __syncthreads();
    buf ^= 1;
  }

  // cross-lane sum (once): combine the 4 q-groups per sample.
  #pragma unroll
  for (int m = 0; m < 4; ++m) {
    S[m] += __shfl_xor(S[m], 16, 64);
    S[m] += __shfl_xor(S[m], 32, 64);
  }

  if (lane < 16) {
    #pragma unroll
    for (int m = 0; m < 4; ++m) {
      int smp = sh * 256 + wid * 64 + m * 16 + lane;
      g_psum[nslot * BATCH + smp] = S[m];
    }
  }
}

// K4a: sum 16 of the 512 partial slots per sample per block (coalesced).
__global__ __launch_bounds__(512) void k4a() {
  int i = threadIdx.x;   // sample
  int b = blockIdx.x;    // chunk of partial slots
  float S = 0.0f;
  #pragma unroll 4
  for (int p = b * K4CHUNK; p < b * K4CHUNK + K4CHUNK; ++p)
    S += g_psum[p * BATCH + i];
  g_qs[b * BATCH + i] = S;
}

// K4b: chunk sum + margins (min/max of norms) + target-logit fixup +
// weighted mean. Fixed max K2C_ (log2 domain): lse = 32 + ln(S2).
__global__ void k4b(const float* __restrict__ wts, float* __restrict__ out) {
  int i = threadIdx.x;  // 512
  float S = 0.0f;
  #pragma unroll
  for (int t = 0; t < NK4; ++t) S += g_qs[t * BATCH + i];

  float n = g_norms[i];
  __shared__ float smin[512], smax[512];
  smin[i] = n; smax[i] = n;
  __syncthreads();
  for (int st = 256; st > 0; st >>= 1) {
    if (i < st) {
      smin[i] = fminf(smin[i], smin[i + st]);
      smax[i] = fmaxf(smax[i], smax[i + st]);
    }
    __syncthreads();
  }
  float lo = smin[0], hi = smax[0];
  float denom = fmaxf(hi - lo, 1e-8f);
  float mg = MMIN_ + (M0_ - MMIN_) * (n - lo) / denom;
  mg = fminf(fmaxf(mg, MMIN_), M0_);

  const float CLIP = 1.0f - 1e-7f;
  float wn = fmaxf(sqrtf(g_wn2[i]), 1e-12f);
  float ct = g_dot[i] / (fmaxf(n, 1e-12f) * wn);
  ct = fminf(fmaxf(ct, -CLIP), CLIP);

  float sint = sqrtf(fmaxf(0.0f, 1.0f - ct * ct));
  float cosm = ct * cosf(mg) - sint * sinf(mg);
  float b_old = K2C_ * ct;            // log2-domain target logits
  float b_new = K2C_ * cosm;
  float S2 = S - ex2(b_old - K2C_) + ex2(b_new - K2C_);
  float lse = 32.0f + logf(S2);       // natural-log lse (K2C_*ln2 = 32)
  float contrib = (lse - SCALE_ * cosm) * wts[i];
  __shared__ float sred[512];
  sred[i] = contrib;
  __syncthreads();
  for (int st = 256; st > 0; st >>= 1) {
    if (i < st) sred[i] += sred[i + st];
    __syncthreads();
  }
  if (i == 0) out[0] = sred[0] * (1.0f / (float)BATCH);
}

extern "C" void kernel_launch(void* const* d_in, const int* in_sizes, int n_in,
                              void* d_out, int out_size, void* d_ws, size_t ws_size,
                              hipStream_t stream) {
  const float* feat = (const float*)d_in[0];
  const float* wmat = (const float*)d_in[1];
  const float* wts  = (const float*)d_in[2];
  const void*  labs = d_in[3];
  float* out = (float*)d_out;

  hipLaunchKernelGGL(k12, dim3(256), dim3(256), 0, stream, feat, wmat, labs);
  hipLaunchKernelGGL(k3,  dim3(1024), dim3(256), 0, stream, wmat);
  hipLaunchKernelGGL(k4a, dim3(NK4), dim3(512), 0, stream);
  hipLaunchKernelGGL(k4b, dim3(1), dim3(512), 0, stream, wts, out);
}

// Round 15
// 76.277 us; speedup vs baseline: 3.3377x; 3.3377x over previous
//
#include <hip/hip_runtime.h>
#include <hip/hip_bf16.h>
#include <math.h>

#define BATCH 512
#define FEAT  256
#define NCLS  100000
#define SCALE_ 32.0f
#define M0_    0.5f
#define MMIN_  0.25f

#define BN 32                        // classes per tile (100000 = 3125*32, no edge)
#define NT32 3125                    // exact tile count
#define NSLOTS 512                   // class-tile slots (stride)
#define NPART 512                    // partial slots per sample
#define K4CHUNK 16
#define NK4 (NPART / K4CHUNK)        // 32

#define LOG2E_ 1.44269504088896f
#define K2C_   (SCALE_ * LOG2E_)     // 46.166...; fixed softmax max (log2 domain)

typedef unsigned short u16;
typedef short s16x8 __attribute__((ext_vector_type(8)));
typedef float f32x4 __attribute__((ext_vector_type(4)));

// ---- static device scratch ----
__device__ u16   g_fbf16[BATCH * FEAT];    // normalized features, bf16
__device__ float g_norms[BATCH];
__device__ float g_dot[BATCH];             // raw f32 feat . W[label]
__device__ float g_wn2[BATCH];             // ||W[label]||^2 (f32)
__device__ float g_psum[NPART * BATCH];    // fixed-max partial sums
__device__ float g_qs[NK4 * BATCH];

__device__ __forceinline__ u16 f2b(float x) {
  union { float f; unsigned u; } v; v.f = x;
  unsigned r = v.u + 0x7FFFu + ((v.u >> 16) & 1u);   // RNE
  return (u16)(r >> 16);
}

// packed f32x2 -> bf16x2 (lo = a, hi = b)
__device__ __forceinline__ unsigned pkbf16(float a, float b) {
  unsigned r;
  asm("v_cvt_pk_bf16_f32 %0, %1, %2" : "=v"(r) : "v"(a), "v"(b));
  return r;
}

__device__ __forceinline__ float ex2(float x) {
  return __builtin_amdgcn_exp2f(x);
}

// K12 (merged k1a + k2c, data-independent halves):
// blocks 0..127: per-row feature norm -> NORMALIZED bf16 row + g_norms.
// blocks 128..255: raw f32 dot(feat_i, W[label_i]) and ||W[label_i]||^2;
//   label width (int32 vs int64) detected locally per wave.
__global__ void k12(const float* __restrict__ feat, const float* __restrict__ wmat,
                    const void* __restrict__ labels) {
  int b = blockIdx.x;
  int wid = threadIdx.x >> 6, lane = threadIdx.x & 63;
  if (b < 128) {
    int row = b * 4 + wid;
    float4 f = ((const float4*)(feat + row * FEAT))[lane];
    float ss = f.x * f.x + f.y * f.y + f.z * f.z + f.w * f.w;
    #pragma unroll
    for (int d = 1; d < 64; d <<= 1) ss += __shfl_xor(ss, d, 64);
    float nrm = sqrtf(ss);
    float inv = 1.0f / fmaxf(nrm, 1e-12f);
    ushort4 h;
    h.x = f2b(f.x * inv); h.y = f2b(f.y * inv);
    h.z = f2b(f.z * inv); h.w = f2b(f.w * inv);
    ((ushort4*)(g_fbf16 + row * FEAT))[lane] = h;
    if (lane == 0) g_norms[row] = nrm;
  } else {
    int i = (b - 128) * 4 + wid;
    const int* labw = (const int*)labels;
    int odd = 0;
    #pragma unroll
    for (int k = 0; k < 4; ++k) odd |= labw[2 * (k * 64 + lane) + 1];
    unsigned long long bl = __ballot(odd != 0);
    long long lab;
    if (bl != 0ULL) lab = (long long)((const int*)labels)[i];
    else            lab = ((const long long*)labels)[i];
    float4 a = ((const float4*)(feat + i * FEAT))[lane];
    float4 w = ((const float4*)(wmat + (size_t)lab * FEAT))[lane];
    float d  = a.x * w.x + a.y * w.y + a.z * w.z + a.w * w.w;
    float bb = w.x * w.x + w.y * w.y + w.z * w.z + w.w * w.w;
    #pragma unroll
    for (int t = 1; t < 64; t <<= 1) {
      d  += __shfl_xor(d, t, 64);
      bb += __shfl_xor(bb, t, 64);
    }
    if (lane == 0) { g_dot[i] = d; g_wn2[i] = bb; }
  }
}

// K3 (fused): 1024 blocks x 512 threads, m=2 (fr[2][8]=64 VGPR, measured
// VGPR=64 -> up to 8 waves/SIMD; LDS 32 KB/block -> 4 blocks/CU possible).
// DECONFOUNDED residency test: bid decode puts same-tile-stream pairs 256
// apart (grp=bid>>8; sh=grp&1; nslot=(bid&255)+((grp>>1)<<8)), so CU c
// hosts streams {c, c, c+256, c+256} -> W re-read L2-deduped (FETCH ~51 MB)
// at EITHER 2- or 4-block residency; time delta purely measures residency.
// W read RAW f32, normalized in-flight, bf16 -> swizzled LDS (2x16 KB dbuf).
// LOAD(t+1) at iter start (16 transient VGPR), FINISH between phases (T14).
// FIXED-MAX softmax in exp2 domain: plain sums; q-group sum once at end.

#define LOADC(TILE) do {                                                    \
    rowL_ = tid >> 4;                                                       \
    int rg_ = (TILE) * BN + rowL_;                                          \
    const float4* src_ = (const float4*)(wmat + (size_t)rg_ * FEAT + (tid & 15) * 16); \
    v_[0] = src_[0]; v_[1] = src_[1]; v_[2] = src_[2]; v_[3] = src_[3];     \
  } while (0)

#define FINISHC(NB) do {                                                    \
    float ss_ = 0.0f;                                                       \
    _Pragma("unroll")                                                       \
    for (int k_ = 0; k_ < 4; ++k_)                                          \
      ss_ += v_[k_].x * v_[k_].x + v_[k_].y * v_[k_].y                      \
           + v_[k_].z * v_[k_].z + v_[k_].w * v_[k_].w;                     \
    ss_ += __shfl_xor(ss_, 1, 64);                                          \
    ss_ += __shfl_xor(ss_, 2, 64);                                          \
    ss_ += __shfl_xor(ss_, 4, 64);                                          \
    ss_ += __shfl_xor(ss_, 8, 64);                                          \
    float inv_ = 1.0f / fmaxf(sqrtf(ss_), 1e-12f);                          \
    u16* dst_ = &Ws[NB][0] + rowL_ * FEAT;                                  \
    _Pragma("unroll")                                                       \
    for (int k_ = 0; k_ < 2; ++k_) {                                        \
      int jj_ = (tid & 15) * 2 + k_;                                        \
      int4 w4_;                                                             \
      w4_.x = (int)pkbf16(v_[2*k_].x * inv_,   v_[2*k_].y * inv_);          \
      w4_.y = (int)pkbf16(v_[2*k_].z * inv_,   v_[2*k_].w * inv_);          \
      w4_.z = (int)pkbf16(v_[2*k_+1].x * inv_, v_[2*k_+1].y * inv_);        \
      w4_.w = (int)pkbf16(v_[2*k_+1].z * inv_, v_[2*k_+1].w * inv_);        \
      *(int4*)(dst_ + ((jj_ ^ (rowL_ & 7)) * 8)) = w4_;                     \
    }                                                                       \
  } while (0)

#define PHASE(p8) do {                                                      \
    f32x4 acc[2];                                                           \
    acc[0] = f32x4{0.0f, 0.0f, 0.0f, 0.0f};                                 \
    acc[1] = f32x4{0.0f, 0.0f, 0.0f, 0.0f};                                 \
    const u16* wb = &Ws[buf][0];                                            \
    const int row_ = (p8) * 16 + s;                                         \
    _Pragma("unroll")                                                       \
    for (int c = 0; c < 8; ++c) {                                           \
      int cc = c * 4 + q;                                                   \
      s16x8 wf = *(const s16x8*)(wb + row_ * FEAT + (cc ^ (row_ & 7)) * 8); \
      acc[0] = __builtin_amdgcn_mfma_f32_16x16x32_bf16(wf, fr[0][c], acc[0], 0, 0, 0); \
      acc[1] = __builtin_amdgcn_mfma_f32_16x16x32_bf16(wf, fr[1][c], acc[1], 0, 0, 0); \
    }                                                                       \
    _Pragma("unroll")                                                       \
    for (int m = 0; m < 2; ++m) {                                           \
      float sl = ex2(fmaf(acc[m][0], K2C_, -K2C_))                          \
               + ex2(fmaf(acc[m][1], K2C_, -K2C_))                          \
               + ex2(fmaf(acc[m][2], K2C_, -K2C_))                          \
               + ex2(fmaf(acc[m][3], K2C_, -K2C_));                         \
      S[m] += sl;                                                           \
    }                                                                       \
  } while (0)

__global__ __launch_bounds__(512, 2) void k3(const float* __restrict__ wmat) {
  __shared__ __align__(16) u16 Ws[2][BN * FEAT];   // 2 x 16 KB

  const int tid  = threadIdx.x;
  const int lane = tid & 63, wid = tid >> 6;
  const int s = lane & 15, q = lane >> 4;
  const int bid = blockIdx.x;
  const int grp = bid >> 8;                        // 0..3
  const int sh  = grp & 1;                         // sample half
  const int nslot = (bid & 255) + ((grp >> 1) << 8);   // 0..511
  const int niter = ((NT32 - 1 - nslot) >> 9) + 1; // 7 (nslot<53) or 6

  int rowL_;
  float4 v_[4];

  // prologue: stage tile `nslot` into buf 0
  LOADC(nslot); FINISHC(0);

  // feature fragments (B-operand): 32 samples per wave, register-resident.
  s16x8 fr[2][8];
  {
    const int srow = sh * 256 + wid * 32;
    #pragma unroll
    for (int m = 0; m < 2; ++m)
      #pragma unroll
      for (int c = 0; c < 8; ++c)
        fr[m][c] = *(const s16x8*)(g_fbf16 + (srow + m * 16 + s) * FEAT + c * 32 + q * 8);
  }

  float S[2] = {0.0f, 0.0f};

  __syncthreads();

  int buf = 0;
  for (int t = 0; t < niter; ++t) {
    const bool last = (t + 1 == niter);

    if (!last) LOADC(nslot + (t + 1) * NSLOTS);
    PHASE(0);
    if (!last) FINISHC(buf ^ 1);
    PHASE(1);
    __syncthreads();
    buf ^= 1;
  }

  // cross-lane sum (once): combine the 4 q-groups per sample.
  #pragma unroll
  for (int m = 0; m < 2; ++m) {
    S[m] += __shfl_xor(S[m], 16, 64);
    S[m] += __shfl_xor(S[m], 32, 64);
  }

  if (lane < 16) {
    #pragma unroll
    for (int m = 0; m < 2; ++m) {
      int smp = sh * 256 + wid * 32 + m * 16 + lane;
      g_psum[nslot * BATCH + smp] = S[m];
    }
  }
}

// K4a: sum 16 of the 512 partial slots per sample per block (coalesced).
__global__ __launch_bounds__(512) void k4a() {
  int i = threadIdx.x;   // sample
  int b = blockIdx.x;    // chunk of partial slots
  float S = 0.0f;
  #pragma unroll 4
  for (int p = b * K4CHUNK; p < b * K4CHUNK + K4CHUNK; ++p)
    S += g_psum[p * BATCH + i];
  g_qs[b * BATCH + i] = S;
}

// K4b: chunk sum + margins (min/max of norms) + target-logit fixup +
// weighted mean. Fixed max K2C_ (log2 domain): lse = 32 + ln(S2).
__global__ void k4b(const float* __restrict__ wts, float* __restrict__ out) {
  int i = threadIdx.x;  // 512
  float S = 0.0f;
  #pragma unroll
  for (int t = 0; t < NK4; ++t) S += g_qs[t * BATCH + i];

  float n = g_norms[i];
  __shared__ float smin[512], smax[512];
  smin[i] = n; smax[i] = n;
  __syncthreads();
  for (int st = 256; st > 0; st >>= 1) {
    if (i < st) {
      smin[i] = fminf(smin[i], smin[i + st]);
      smax[i] = fmaxf(smax[i], smax[i + st]);
    }
    __syncthreads();
  }
  float lo = smin[0], hi = smax[0];
  float denom = fmaxf(hi - lo, 1e-8f);
  float mg = MMIN_ + (M0_ - MMIN_) * (n - lo) / denom;
  mg = fminf(fmaxf(mg, MMIN_), M0_);

  const float CLIP = 1.0f - 1e-7f;
  float wn = fmaxf(sqrtf(g_wn2[i]), 1e-12f);
  float ct = g_dot[i] / (fmaxf(n, 1e-12f) * wn);
  ct = fminf(fmaxf(ct, -CLIP), CLIP);

  float sint = sqrtf(fmaxf(0.0f, 1.0f - ct * ct));
  float cosm = ct * cosf(mg) - sint * sinf(mg);
  float b_old = K2C_ * ct;            // log2-domain target logits
  float b_new = K2C_ * cosm;
  float S2 = S - ex2(b_old - K2C_) + ex2(b_new - K2C_);
  float lse = 32.0f + logf(S2);       // natural-log lse (K2C_*ln2 = 32)
  float contrib = (lse - SCALE_ * cosm) * wts[i];
  __shared__ float sred[512];
  sred[i] = contrib;
  __syncthreads();
  for (int st = 256; st > 0; st >>= 1) {
    if (i < st) sred[i] += sred[i + st];
    __syncthreads();
  }
  if (i == 0) out[0] = sred[0] * (1.0f / (float)BATCH);
}

extern "C" void kernel_launch(void* const* d_in, const int* in_sizes, int n_in,
                              void* d_out, int out_size, void* d_ws, size_t ws_size,
                              hipStream_t stream) {
  const float* feat = (const float*)d_in[0];
  const float* wmat = (const float*)d_in[1];
  const float* wts  = (const float*)d_in[2];
  const void*  labs = d_in[3];
  float* out = (float*)d_out;

  hipLaunchKernelGGL(k12, dim3(256), dim3(256), 0, stream, feat, wmat, labs);
  hipLaunchKernelGGL(k3,  dim3(1024), dim3(512), 0, stream, wmat);
  hipLaunchKernelGGL(k4a, dim3(NK4), dim3(512), 0, stream);
  hipLaunchKernelGGL(k4b, dim3(1), dim3(512), 0, stream, wts, out);
}

// Round 16
// 54.858 us; speedup vs baseline: 4.6408x; 1.3904x over previous
//
#include <hip/hip_runtime.h>
#include <hip/hip_bf16.h>
#include <math.h>

#define BATCH 512
#define FEAT  256
#define NCLS  100000
#define SCALE_ 32.0f
#define M0_    0.5f
#define MMIN_  0.25f

#define BN 32                        // classes per tile (100000 = 3125*32, no edge)
#define NT32 3125                    // exact tile count
#define NSLOTS 256                   // class-tile slots (stride)
#define NPART 256                    // partial slots per sample
#define K4CHUNK 16
#define NK4 (NPART / K4CHUNK)        // 16

#define LOG2E_ 1.44269504088896f
#define K2C_   (SCALE_ * LOG2E_)     // 46.166...; fixed softmax max (log2 domain)

typedef unsigned short u16;
typedef short s16x8 __attribute__((ext_vector_type(8)));
typedef float f32x4 __attribute__((ext_vector_type(4)));

// ---- static device scratch ----
__device__ u16   g_fbf16[BATCH * FEAT];    // normalized features, bf16
__device__ float g_norms[BATCH];
__device__ float g_dot[BATCH];             // raw f32 feat . W[label]
__device__ float g_wn2[BATCH];             // ||W[label]||^2 (f32)
__device__ float g_psum[NPART * BATCH];    // fixed-max partial sums
__device__ float g_qs[NK4 * BATCH];

__device__ __forceinline__ u16 f2b(float x) {
  union { float f; unsigned u; } v; v.f = x;
  unsigned r = v.u + 0x7FFFu + ((v.u >> 16) & 1u);   // RNE
  return (u16)(r >> 16);
}

// packed f32x2 -> bf16x2 (lo = a, hi = b)
__device__ __forceinline__ unsigned pkbf16(float a, float b) {
  unsigned r;
  asm("v_cvt_pk_bf16_f32 %0, %1, %2" : "=v"(r) : "v"(a), "v"(b));
  return r;
}

__device__ __forceinline__ float ex2(float x) {
  return __builtin_amdgcn_exp2f(x);
}

// K12 (merged k1a + k2c, data-independent halves):
// blocks 0..127: per-row feature norm -> NORMALIZED bf16 row + g_norms.
// blocks 128..255: raw f32 dot(feat_i, W[label_i]) and ||W[label_i]||^2;
//   label width (int32 vs int64) detected locally per wave.
__global__ void k12(const float* __restrict__ feat, const float* __restrict__ wmat,
                    const void* __restrict__ labels) {
  int b = blockIdx.x;
  int wid = threadIdx.x >> 6, lane = threadIdx.x & 63;
  if (b < 128) {
    int row = b * 4 + wid;
    float4 f = ((const float4*)(feat + row * FEAT))[lane];
    float ss = f.x * f.x + f.y * f.y + f.z * f.z + f.w * f.w;
    #pragma unroll
    for (int d = 1; d < 64; d <<= 1) ss += __shfl_xor(ss, d, 64);
    float nrm = sqrtf(ss);
    float inv = 1.0f / fmaxf(nrm, 1e-12f);
    ushort4 h;
    h.x = f2b(f.x * inv); h.y = f2b(f.y * inv);
    h.z = f2b(f.z * inv); h.w = f2b(f.w * inv);
    ((ushort4*)(g_fbf16 + row * FEAT))[lane] = h;
    if (lane == 0) g_norms[row] = nrm;
  } else {
    int i = (b - 128) * 4 + wid;
    const int* labw = (const int*)labels;
    int odd = 0;
    #pragma unroll
    for (int k = 0; k < 4; ++k) odd |= labw[2 * (k * 64 + lane) + 1];
    unsigned long long bl = __ballot(odd != 0);
    long long lab;
    if (bl != 0ULL) lab = (long long)((const int*)labels)[i];
    else            lab = ((const long long*)labels)[i];
    float4 a = ((const float4*)(feat + i * FEAT))[lane];
    float4 w = ((const float4*)(wmat + (size_t)lab * FEAT))[lane];
    float d  = a.x * w.x + a.y * w.y + a.z * w.z + a.w * w.w;
    float bb = w.x * w.x + w.y * w.y + w.z * w.z + w.w * w.w;
    #pragma unroll
    for (int t = 1; t < 64; t <<= 1) {
      d  += __shfl_xor(d, t, 64);
      bb += __shfl_xor(bb, t, 64);
    }
    if (lane == 0) { g_dot[i] = d; g_wn2[i] = bb; }
  }
}

// K3 (fused): R12 geometry exactly (512 blocks x 256 threads, m=4, BN=32,
// FETCH-deduped sh-pairing) + two schedule edits:
//  (1) split-FINISH: FINHALF(0) between P0/P1 (as before); FINHALF(1) moved
//      AFTER P1 -> its global-load-to-use distance spans both phases
//      (~1000 cyc > ~900-cyc HBM latency) -> vmcnt stall halved.
//  (2) T5: s_setprio(1) around the MFMA c-loop. The CU hosts 2 independent
//      blocks at different phases (role diversity), the regime where
//      setprio measured positive.
// Everything else identical to R12 (proven correct, no spill, VGPR 124).

#define LOADC(TILE) do {                                                    \
    rowL_ = tid >> 4;                                                       \
    const float4* s0_ = (const float4*)(wmat + (size_t)((TILE) * BN + rowL_) * FEAT + (tid & 15) * 16);      \
    const float4* s1_ = (const float4*)(wmat + (size_t)((TILE) * BN + 16 + rowL_) * FEAT + (tid & 15) * 16); \
    v_[0] = s0_[0]; v_[1] = s0_[1]; v_[2] = s0_[2]; v_[3] = s0_[3];         \
    v_[4] = s1_[0]; v_[5] = s1_[1]; v_[6] = s1_[2]; v_[7] = s1_[3];         \
  } while (0)

#define FINHALF(NB, G, ROW) do {                                            \
    float ss_ = 0.0f;                                                       \
    _Pragma("unroll")                                                       \
    for (int k_ = 0; k_ < 4; ++k_) {                                        \
      float4 vv_ = v_[(G) * 4 + k_];                                        \
      ss_ += vv_.x * vv_.x + vv_.y * vv_.y + vv_.z * vv_.z + vv_.w * vv_.w; \
    }                                                                       \
    ss_ += __shfl_xor(ss_, 1, 64);                                          \
    ss_ += __shfl_xor(ss_, 2, 64);                                          \
    ss_ += __shfl_xor(ss_, 4, 64);                                          \
    ss_ += __shfl_xor(ss_, 8, 64);                                          \
    float inv_ = 1.0f / fmaxf(sqrtf(ss_), 1e-12f);                          \
    u16* dst_ = &Ws[NB][0] + (ROW) * FEAT;                                  \
    _Pragma("unroll")                                                       \
    for (int k_ = 0; k_ < 2; ++k_) {                                        \
      int jj_ = (tid & 15) * 2 + k_;                                        \
      float4 va_ = v_[(G) * 4 + 2 * k_], vb_ = v_[(G) * 4 + 2 * k_ + 1];    \
      int4 w4_;                                                             \
      w4_.x = (int)pkbf16(va_.x * inv_, va_.y * inv_);                      \
      w4_.y = (int)pkbf16(va_.z * inv_, va_.w * inv_);                      \
      w4_.z = (int)pkbf16(vb_.x * inv_, vb_.y * inv_);                      \
      w4_.w = (int)pkbf16(vb_.z * inv_, vb_.w * inv_);                      \
      *(int4*)(dst_ + ((jj_ ^ ((ROW) & 7)) * 8)) = w4_;                     \
    }                                                                       \
  } while (0)

#define PHASE(p8) do {                                                      \
    f32x4 acc[4];                                                           \
    _Pragma("unroll")                                                       \
    for (int m = 0; m < 4; ++m) acc[m] = f32x4{0.0f, 0.0f, 0.0f, 0.0f};     \
    const u16* wb = &Ws[buf][0];                                            \
    const int row_ = (p8) * 16 + s;                                         \
    __builtin_amdgcn_s_setprio(1);                                          \
    _Pragma("unroll")                                                       \
    for (int c = 0; c < 8; ++c) {                                           \
      int cc = c * 4 + q;                                                   \
      s16x8 wf = *(const s16x8*)(wb + row_ * FEAT + (cc ^ (row_ & 7)) * 8); \
      _Pragma("unroll")                                                     \
      for (int m = 0; m < 4; ++m)                                           \
        acc[m] = __builtin_amdgcn_mfma_f32_16x16x32_bf16(wf, fr[m][c], acc[m], 0, 0, 0); \
    }                                                                       \
    __builtin_amdgcn_s_setprio(0);                                          \
    _Pragma("unroll")                                                       \
    for (int m = 0; m < 4; ++m) {                                           \
      float sl = ex2(fmaf(acc[m][0], K2C_, -K2C_))                          \
               + ex2(fmaf(acc[m][1], K2C_, -K2C_))                          \
               + ex2(fmaf(acc[m][2], K2C_, -K2C_))                          \
               + ex2(fmaf(acc[m][3], K2C_, -K2C_));                         \
      S[m] += sl;                                                           \
    }                                                                       \
  } while (0)

__global__ __launch_bounds__(256, 1) void k3(const float* __restrict__ wmat) {
  __shared__ __align__(16) u16 Ws[2][BN * FEAT];   // 2 x 16 KB

  const int tid  = threadIdx.x;
  const int lane = tid & 63, wid = tid >> 6;       // 4 waves
  const int s = lane & 15, q = lane >> 4;
  const int bid = blockIdx.x;
  const int nslot = bid & 255;
  const int sh = bid >> 8;                         // sample half
  const int niter = ((NT32 - 1 - nslot) >> 8) + 1; // 13 (nslot<53) or 12

  int rowL_;
  float4 v_[8];

  // prologue: stage tile `nslot` into buf 0
  LOADC(nslot);
  FINHALF(0, 0, rowL_);
  FINHALF(0, 1, 16 + rowL_);

  // feature fragments (B-operand): 64 samples per wave, register-resident.
  s16x8 fr[4][8];
  {
    const int srow = sh * 256 + wid * 64;
    #pragma unroll
    for (int m = 0; m < 4; ++m)
      #pragma unroll
      for (int c = 0; c < 8; ++c)
        fr[m][c] = *(const s16x8*)(g_fbf16 + (srow + m * 16 + s) * FEAT + c * 32 + q * 8);
  }

  float S[4] = {0.0f, 0.0f, 0.0f, 0.0f};

  __syncthreads();

  int buf = 0;
  for (int t = 0; t < niter; ++t) {
    const bool last = (t + 1 == niter);

    if (!last) LOADC(nslot + (t + 1) * NSLOTS);
    PHASE(0);
    if (!last) FINHALF(buf ^ 1, 0, rowL_);
    PHASE(1);
    if (!last) FINHALF(buf ^ 1, 1, 16 + rowL_);
    __syncthreads();
    buf ^= 1;
  }

  // cross-lane sum (once): combine the 4 q-groups per sample.
  #pragma unroll
  for (int m = 0; m < 4; ++m) {
    S[m] += __shfl_xor(S[m], 16, 64);
    S[m] += __shfl_xor(S[m], 32, 64);
  }

  if (lane < 16) {
    #pragma unroll
    for (int m = 0; m < 4; ++m) {
      int smp = sh * 256 + wid * 64 + m * 16 + lane;
      g_psum[nslot * BATCH + smp] = S[m];
    }
  }
}

// K4a: sum 16 of the 256 partial slots per sample per block (coalesced).
__global__ __launch_bounds__(512) void k4a() {
  int i = threadIdx.x;   // sample
  int b = blockIdx.x;    // chunk of partial slots
  float S = 0.0f;
  #pragma unroll 4
  for (int p = b * K4CHUNK; p < b * K4CHUNK + K4CHUNK; ++p)
    S += g_psum[p * BATCH + i];
  g_qs[b * BATCH + i] = S;
}

// K4b: chunk sum + margins (min/max of norms) + target-logit fixup +
// weighted mean. Fixed max K2C_ (log2 domain): lse = 32 + ln(S2).
__global__ void k4b(const float* __restrict__ wts, float* __restrict__ out) {
  int i = threadIdx.x;  // 512
  float S = 0.0f;
  #pragma unroll
  for (int t = 0; t < NK4; ++t) S += g_qs[t * BATCH + i];

  float n = g_norms[i];
  __shared__ float smin[512], smax[512];
  smin[i] = n; smax[i] = n;
  __syncthreads();
  for (int st = 256; st > 0; st >>= 1) {
    if (i < st) {
      smin[i] = fminf(smin[i], smin[i + st]);
      smax[i] = fmaxf(smax[i], smax[i + st]);
    }
    __syncthreads();
  }
  float lo = smin[0], hi = smax[0];
  float denom = fmaxf(hi - lo, 1e-8f);
  float mg = MMIN_ + (M0_ - MMIN_) * (n - lo) / denom;
  mg = fminf(fmaxf(mg, MMIN_), M0_);

  const float CLIP = 1.0f - 1e-7f;
  float wn = fmaxf(sqrtf(g_wn2[i]), 1e-12f);
  float ct = g_dot[i] / (fmaxf(n, 1e-12f) * wn);
  ct = fminf(fmaxf(ct, -CLIP), CLIP);

  float sint = sqrtf(fmaxf(0.0f, 1.0f - ct * ct));
  float cosm = ct * cosf(mg) - sint * sinf(mg);
  float b_old = K2C_ * ct;            // log2-domain target logits
  float b_new = K2C_ * cosm;
  float S2 = S - ex2(b_old - K2C_) + ex2(b_new - K2C_);
  float lse = 32.0f + logf(S2);       // natural-log lse (K2C_*ln2 = 32)
  float contrib = (lse - SCALE_ * cosm) * wts[i];
  __shared__ float sred[512];
  sred[i] = contrib;
  __syncthreads();
  for (int st = 256; st > 0; st >>= 1) {
    if (i < st) sred[i] += sred[i + st];
    __syncthreads();
  }
  if (i == 0) out[0] = sred[0] * (1.0f / (float)BATCH);
}

extern "C" void kernel_launch(void* const* d_in, const int* in_sizes, int n_in,
                              void* d_out, int out_size, void* d_ws, size_t ws_size,
                              hipStream_t stream) {
  const float* feat = (const float*)d_in[0];
  const float* wmat = (const float*)d_in[1];
  const float* wts  = (const float*)d_in[2];
  const void*  labs = d_in[3];
  float* out = (float*)d_out;

  hipLaunchKernelGGL(k12, dim3(256), dim3(256), 0, stream, feat, wmat, labs);
  hipLaunchKernelGGL(k3,  dim3(512), dim3(256), 0, stream, wmat);
  hipLaunchKernelGGL(k4a, dim3(NK4), dim3(512), 0, stream);
  hipLaunchKernelGGL(k4b, dim3(1), dim3(512), 0, stream, wts, out);
}